// Round 1
// baseline (345.054 us; speedup 1.0000x reference)
//
#include <hip/hip_runtime.h>
#include <hip/hip_bf16.h>

#define TOKENS 4096
#define HDIM 1024
#define NEXP 16
#define BM 128
#define BN 128
#define BK 64
#define MAXMT (TOKENS / BM)   // 32

typedef __bf16 bf16x8 __attribute__((ext_vector_type(8)));
typedef float f32x4 __attribute__((ext_vector_type(4)));

// ---------------- Gate: logits (fp32 exact), softmax, top-2, counts ----------------
__global__ __launch_bounds__(256) void gate_kernel(
    const float* __restrict__ tokens, const float* __restrict__ gate_w,
    int* __restrict__ counts, int* __restrict__ tok_idx, float* __restrict__ tok_w) {
  int lane = threadIdx.x & 63;
  int wv = threadIdx.x >> 6;
  int token = blockIdx.x * 4 + wv;   // grid = TOKENS/4
  const float* trow = tokens + (size_t)token * HDIM;

  float tv[16];
#pragma unroll
  for (int i = 0; i < 4; ++i) {
    float4 v = *(const float4*)(trow + lane * 16 + i * 4);
    tv[i * 4 + 0] = v.x; tv[i * 4 + 1] = v.y; tv[i * 4 + 2] = v.z; tv[i * 4 + 3] = v.w;
  }

  float lg[NEXP];
#pragma unroll
  for (int e = 0; e < NEXP; ++e) {
    const float* grow = gate_w + e * HDIM + lane * 16;
    float d = 0.f;
#pragma unroll
    for (int i = 0; i < 4; ++i) {
      float4 v = *(const float4*)(grow + i * 4);
      d += tv[i * 4 + 0] * v.x + tv[i * 4 + 1] * v.y + tv[i * 4 + 2] * v.z + tv[i * 4 + 3] * v.w;
    }
#pragma unroll
    for (int off = 32; off; off >>= 1) d += __shfl_xor(d, off);
    lg[e] = d;
  }

  // top-2 on logits (monotone in softmax). Strict > keeps lowest index on ties (matches top_k).
  int i0 = 0; float b0 = lg[0];
#pragma unroll
  for (int e = 1; e < NEXP; ++e) if (lg[e] > b0) { b0 = lg[e]; i0 = e; }
  int i1 = -1; float b1 = -1e30f;
#pragma unroll
  for (int e = 0; e < NEXP; ++e) {
    if (e == i0) continue;
    if (lg[e] > b1) { b1 = lg[e]; i1 = e; }
  }
  // softmax weights (fp32)
  float mx = b0;
  float s = 0.f;
#pragma unroll
  for (int e = 0; e < NEXP; ++e) s += expf(lg[e] - mx);
  float w0 = expf(b0 - mx) / s;
  float w1 = expf(b1 - mx) / s;

  if (lane == 0) {
    tok_idx[token * 2 + 0] = i0;
    tok_idx[token * 2 + 1] = i1;
    tok_w[token * 2 + 0] = w0;
    tok_w[token * 2 + 1] = w1;
    atomicAdd(&counts[i0], 1);
    atomicAdd(&counts[i1], 1);
  }
}

// ---------------- Prefix scan over 16 counts ----------------
__global__ void scan_kernel(const int* __restrict__ counts, int* __restrict__ offsets,
                            int* __restrict__ cursor) {
  if (threadIdx.x == 0) {
    int acc = 0;
    for (int e = 0; e < NEXP; ++e) { offsets[e] = acc; cursor[e] = acc; acc += counts[e]; }
  }
}

// ---------------- Scatter token ids into per-expert lists ----------------
__global__ __launch_bounds__(256) void scatter_kernel(
    const int* __restrict__ tok_idx, const float* __restrict__ tok_w,
    int* __restrict__ cursor, int* __restrict__ list_tok, float* __restrict__ list_w) {
  int t = blockIdx.x * 256 + threadIdx.x;
  if (t >= TOKENS) return;
#pragma unroll
  for (int k = 0; k < 2; ++k) {
    int e = tok_idx[t * 2 + k];
    int pos = atomicAdd(&cursor[e], 1);
    list_tok[pos] = t;
    list_w[pos] = tok_w[t * 2 + k];
  }
}

// ---------------- Grouped GEMM: out[tok] += gw * relu(x @ W[e]^T + b[e]) ----------------
__global__ __launch_bounds__(256) void moe_gemm_kernel(
    const float* __restrict__ tokens, const float* __restrict__ expert_w,
    const float* __restrict__ expert_b, const int* __restrict__ counts,
    const int* __restrict__ offsets, const int* __restrict__ list_tok,
    const float* __restrict__ list_w, float* __restrict__ out) {
  int e = blockIdx.x & 15;
  int mt = blockIdx.x >> 4;
  int cnt = counts[e];
  if (mt * BM >= cnt) return;
  int off = offsets[e];
  int nt = blockIdx.y;

  __shared__ __bf16 Ald[BM * BK];
  __shared__ __bf16 Bld[BN * BK];

  int tid = threadIdx.x;

  // Staging map: chunk c = tid + i*256  (c in [0,1024)): row = c>>3, kchunk = c&7.
  // XOR swizzle on 16B chunks: kc' = kc ^ (row&7)  (breaks 128B-stride bank conflicts).
  const float* asrc[4];
  int aoff[4];
  const float* bsrc[4];
  int boff[4];
#pragma unroll
  for (int i = 0; i < 4; ++i) {
    int c = tid + i * 256;
    int r = c >> 3, kc = c & 7;
    int gr = mt * BM + r;
    int tok = list_tok[off + ((gr < cnt) ? gr : 0)];
    asrc[i] = tokens + (size_t)tok * HDIM + kc * 8;
    aoff[i] = r * BK + ((kc ^ (r & 7)) * 8);
    int d = nt * BN + r;
    bsrc[i] = expert_w + (size_t)e * HDIM * HDIM + (size_t)d * HDIM + kc * 8;
    boff[i] = r * BK + ((kc ^ (r & 7)) * 8);
  }

  int lane = tid & 63;
  int wv = tid >> 6;
  int wr = (wv >> 1) * 64;   // wave row offset in tile
  int wc = (wv & 1) * 64;    // wave col offset in tile
  int lr = lane & 15;
  int lk = lane >> 4;

  f32x4 acc[4][4] = {};

  for (int kb = 0; kb < HDIM / BK; ++kb) {
    int kbase = kb * BK;
#pragma unroll
    for (int i = 0; i < 4; ++i) {
      float4 f0 = *(const float4*)(asrc[i] + kbase);
      float4 f1 = *(const float4*)(asrc[i] + kbase + 4);
      bf16x8 v;
      v[0] = (__bf16)f0.x; v[1] = (__bf16)f0.y; v[2] = (__bf16)f0.z; v[3] = (__bf16)f0.w;
      v[4] = (__bf16)f1.x; v[5] = (__bf16)f1.y; v[6] = (__bf16)f1.z; v[7] = (__bf16)f1.w;
      *(bf16x8*)(&Ald[aoff[i]]) = v;
    }
#pragma unroll
    for (int i = 0; i < 4; ++i) {
      float4 f0 = *(const float4*)(bsrc[i] + kbase);
      float4 f1 = *(const float4*)(bsrc[i] + kbase + 4);
      bf16x8 v;
      v[0] = (__bf16)f0.x; v[1] = (__bf16)f0.y; v[2] = (__bf16)f0.z; v[3] = (__bf16)f0.w;
      v[4] = (__bf16)f1.x; v[5] = (__bf16)f1.y; v[6] = (__bf16)f1.z; v[7] = (__bf16)f1.w;
      *(bf16x8*)(&Bld[boff[i]]) = v;
    }
    __syncthreads();

    bf16x8 af[2][4], bfr[2][4];
#pragma unroll
    for (int kk = 0; kk < 2; ++kk) {
#pragma unroll
      for (int m = 0; m < 4; ++m) {
        int r = wr + m * 16 + lr;
        af[kk][m] = *(const bf16x8*)(&Ald[r * BK + (((kk * 4 + lk) ^ (r & 7)) * 8)]);
        int d = wc + m * 16 + lr;
        bfr[kk][m] = *(const bf16x8*)(&Bld[d * BK + (((kk * 4 + lk) ^ (d & 7)) * 8)]);
      }
    }
#pragma unroll
    for (int kk = 0; kk < 2; ++kk)
#pragma unroll
      for (int m = 0; m < 4; ++m)
#pragma unroll
        for (int n = 0; n < 4; ++n)
          acc[m][n] = __builtin_amdgcn_mfma_f32_16x16x32_bf16(af[kk][m], bfr[kk][n], acc[m][n], 0, 0, 0);
    __syncthreads();
  }

  // Epilogue: C/D layout col = lane&15, row = (lane>>4)*4 + j  [m89/m91]
#pragma unroll
  for (int m = 0; m < 4; ++m) {
#pragma unroll
    for (int j = 0; j < 4; ++j) {
      int rloc = wr + m * 16 + lk * 4 + j;
      int grow = mt * BM + rloc;
      if (grow < cnt) {
        int tok = list_tok[off + grow];
        float gw = list_w[off + grow];
        float* orow = out + (size_t)tok * HDIM + nt * BN + wc;
        const float* brow = expert_b + e * HDIM + nt * BN + wc;
#pragma unroll
        for (int n = 0; n < 4; ++n) {
          int dcol = n * 16 + lr;
          float v = acc[m][n][j] + brow[dcol];
          v = fmaxf(v, 0.f) * gw;
          atomicAdd(orow + dcol, v);
        }
      }
    }
  }
}

extern "C" void kernel_launch(void* const* d_in, const int* in_sizes, int n_in,
                              void* d_out, int out_size, void* d_ws, size_t ws_size,
                              hipStream_t stream) {
  const float* tokens = (const float*)d_in[0];
  const float* gate_w = (const float*)d_in[1];
  const float* expert_w = (const float*)d_in[2];
  const float* expert_b = (const float*)d_in[3];
  float* out = (float*)d_out;

  int* counts = (int*)d_ws;                 // 16
  int* offsets = counts + 16;               // 16
  int* cursor = offsets + 16;               // 16
  int* tok_idx = cursor + 16;               // TOKENS*2
  float* tok_w = (float*)(tok_idx + TOKENS * 2);
  int* list_tok = (int*)(tok_w + TOKENS * 2);
  float* list_w = (float*)(list_tok + TOKENS * 2);

  hipMemsetAsync(counts, 0, 16 * sizeof(int), stream);
  hipMemsetAsync(d_out, 0, (size_t)out_size * sizeof(float), stream);

  gate_kernel<<<TOKENS / 4, 256, 0, stream>>>(tokens, gate_w, counts, tok_idx, tok_w);
  scan_kernel<<<1, 64, 0, stream>>>(counts, offsets, cursor);
  scatter_kernel<<<TOKENS / 256, 256, 0, stream>>>(tok_idx, tok_w, cursor, list_tok, list_w);

  dim3 grid(NEXP * MAXMT, HDIM / BN);
  moe_gemm_kernel<<<grid, 256, 0, stream>>>(tokens, expert_w, expert_b, counts, offsets,
                                            list_tok, list_w, out);
}

// Round 2
// 315.866 us; speedup vs baseline: 1.0924x; 1.0924x over previous
//
#include <hip/hip_runtime.h>
#include <hip/hip_bf16.h>

#define TOKENS 4096
#define HDIM 1024
#define NEXP 16
#define BM 128
#define BN 64
#define BK 64
#define MAXMT (TOKENS / BM)   // 32

typedef __bf16 bf16x8 __attribute__((ext_vector_type(8)));
typedef __bf16 bf16x4 __attribute__((ext_vector_type(4)));
typedef float f32x4 __attribute__((ext_vector_type(4)));

__device__ inline void gload16(const void* g, const void* l) {
  __builtin_amdgcn_global_load_lds((const __attribute__((address_space(1))) void*)g,
                                   (__attribute__((address_space(3))) void*)l, 16, 0, 0);
}

// ---------------- fp32 -> bf16 conversion (weights + tokens) ----------------
#define WQ (NEXP * HDIM * HDIM / 4)   // float4 count for weights: 4,194,304
#define TQ (TOKENS * HDIM / 4)        // 1,048,576
__global__ __launch_bounds__(256) void convert_kernel(
    const float* __restrict__ w, const float* __restrict__ t,
    __bf16* __restrict__ wbf, __bf16* __restrict__ tbf) {
  int idx = blockIdx.x * 256 + threadIdx.x;
  for (int i = idx; i < WQ + TQ; i += gridDim.x * 256) {
    const float4* src;
    bf16x4* dst;
    int j;
    if (i < WQ) { src = (const float4*)w; dst = (bf16x4*)wbf; j = i; }
    else        { src = (const float4*)t; dst = (bf16x4*)tbf; j = i - WQ; }
    float4 f = src[j];
    bf16x4 v;
    v[0] = (__bf16)f.x; v[1] = (__bf16)f.y; v[2] = (__bf16)f.z; v[3] = (__bf16)f.w;
    dst[j] = v;
  }
}

// ---------------- Gate: fp32-exact logits, softmax, top-2 (coalesced) ----------------
__global__ __launch_bounds__(256) void gate_kernel(
    const float* __restrict__ tokens, const float* __restrict__ gate_w,
    int* __restrict__ counts, int* __restrict__ tok_idx, float* __restrict__ tok_w) {
  int lane = threadIdx.x & 63;
  int wv = threadIdx.x >> 6;
  int token = blockIdx.x * 4 + wv;   // grid = TOKENS/4
  const float* trow = tokens + (size_t)token * HDIM;

  float4 tv[4];
#pragma unroll
  for (int s = 0; s < 4; ++s) tv[s] = *(const float4*)(trow + s * 256 + lane * 4);

  float lg[NEXP];
#pragma unroll
  for (int e = 0; e < NEXP; ++e) {
    float d = 0.f;
#pragma unroll
    for (int s = 0; s < 4; ++s) {
      float4 g = *(const float4*)(gate_w + e * HDIM + s * 256 + lane * 4);
      d += tv[s].x * g.x + tv[s].y * g.y + tv[s].z * g.z + tv[s].w * g.w;
    }
#pragma unroll
    for (int off = 32; off; off >>= 1) d += __shfl_xor(d, off);
    lg[e] = d;
  }

  int i0 = 0; float b0 = lg[0];
#pragma unroll
  for (int e = 1; e < NEXP; ++e) if (lg[e] > b0) { b0 = lg[e]; i0 = e; }
  int i1 = -1; float b1 = -1e30f;
#pragma unroll
  for (int e = 0; e < NEXP; ++e) {
    if (e == i0) continue;
    if (lg[e] > b1) { b1 = lg[e]; i1 = e; }
  }
  float s = 0.f;
#pragma unroll
  for (int e = 0; e < NEXP; ++e) s += expf(lg[e] - b0);
  float w0 = expf(b0 - b0) / s;
  float w1 = expf(b1 - b0) / s;

  if (lane == 0) {
    tok_idx[token * 2 + 0] = i0;
    tok_idx[token * 2 + 1] = i1;
    tok_w[token * 2 + 0] = w0;
    tok_w[token * 2 + 1] = w1;
    atomicAdd(&counts[i0], 1);
    atomicAdd(&counts[i1], 1);
  }
}

// ---------------- Prefix scan over 16 counts ----------------
__global__ void scan_kernel(const int* __restrict__ counts, int* __restrict__ offsets,
                            int* __restrict__ cursor) {
  if (threadIdx.x == 0) {
    int acc = 0;
    for (int e = 0; e < NEXP; ++e) { offsets[e] = acc; cursor[e] = acc; acc += counts[e]; }
  }
}

// ---------------- Scatter token ids into per-expert lists ----------------
__global__ __launch_bounds__(256) void scatter_kernel(
    const int* __restrict__ tok_idx, const float* __restrict__ tok_w,
    int* __restrict__ cursor, int* __restrict__ list_tok, float* __restrict__ list_w) {
  int t = blockIdx.x * 256 + threadIdx.x;
  if (t >= TOKENS) return;
#pragma unroll
  for (int k = 0; k < 2; ++k) {
    int e = tok_idx[t * 2 + k];
    int pos = atomicAdd(&cursor[e], 1);
    list_tok[pos] = t;
    list_w[pos] = tok_w[t * 2 + k];
  }
}

// ---------------- Grouped GEMM (bf16, global_load_lds, dbuf, prefetch) ----------------
// LDS layout (per buffer): A[128][64] bf16 then B[64][64] bf16, both row-major with
// XOR swizzle applied via pre-swizzled GLOBAL source column (m173 pattern):
// slot (r, kc) holds G(r, kc ^ (r&7)); reader of G(r,c) reads slot (r, c^(r&7)).
__global__ __launch_bounds__(256) void moe_gemm_kernel(
    const __bf16* __restrict__ tok_bf, const __bf16* __restrict__ w_bf,
    const float* __restrict__ expert_b, const int* __restrict__ counts,
    const int* __restrict__ offsets, const int* __restrict__ list_tok,
    const float* __restrict__ list_w, float* __restrict__ out) {
  int e = blockIdx.x & 15;
  int mt = blockIdx.x >> 4;
  int cnt = counts[e];
  if (mt * BM >= cnt) return;
  int off = offsets[e];
  int nt = blockIdx.y;

  __shared__ __bf16 lds[2][(BM + BN) * BK];   // 2 x 24KB

  int tid = threadIdx.x;
  int lane = tid & 63;
  int wv = tid >> 6;

  // --- staging descriptors ---
  // A: 1024 chunks of 16B; wave w issue i covers chunks [(w*4+i)*64 + lane]
  const __bf16* aptr[4];
  int adst[4];   // elem offset within a buffer
#pragma unroll
  for (int i = 0; i < 4; ++i) {
    int c = (wv * 4 + i) * 64 + lane;
    int r = c >> 3, kc = c & 7;
    int gr = mt * BM + r;
    int tok = list_tok[off + ((gr < cnt) ? gr : (cnt - 1))];
    aptr[i] = tok_bf + (size_t)tok * HDIM + (kc ^ (r & 7)) * 8;
    adst[i] = (wv * 4 + i) * 512;   // wave-uniform base; HW adds lane*16B
  }
  // B: 512 chunks; wave w issue i covers chunks [(w*2+i)*64 + lane]
  const __bf16* bptr[2];
  int bdst[2];
#pragma unroll
  for (int i = 0; i < 2; ++i) {
    int c = (wv * 2 + i) * 64 + lane;
    int r = c >> 3, kc = c & 7;
    int d = nt * BN + r;
    bptr[i] = w_bf + (size_t)e * HDIM * HDIM + (size_t)d * HDIM + (kc ^ (r & 7)) * 8;
    bdst[i] = BM * BK + (wv * 2 + i) * 512;
  }

  int wr = (wv >> 1) * 64;   // wave row offset (0/64)
  int wc = (wv & 1) * 32;    // wave col offset (0/32)
  int lr = lane & 15;
  int lk = lane >> 4;

  // fragment LDS elem offsets (swizzled reads), invariant over kb
  int aoffr[2][4], boffr[2][2];
#pragma unroll
  for (int kk = 0; kk < 2; ++kk) {
#pragma unroll
    for (int m = 0; m < 4; ++m) {
      int r = wr + m * 16 + lr;
      aoffr[kk][m] = r * BK + (((kk * 4 + lk) ^ (r & 7)) * 8);
    }
#pragma unroll
    for (int n = 0; n < 2; ++n) {
      int d = wc + n * 16 + lr;
      boffr[kk][n] = BM * BK + d * BK + (((kk * 4 + lk) ^ (d & 7)) * 8);
    }
  }

  f32x4 acc[4][2] = {};

  // prologue: stage kb=0 into buf 0
#pragma unroll
  for (int i = 0; i < 4; ++i) gload16(aptr[i], &lds[0][adst[i]]);
#pragma unroll
  for (int i = 0; i < 2; ++i) gload16(bptr[i], &lds[0][bdst[i]]);
  __syncthreads();

  int buf = 0;
  for (int kb = 0; kb < HDIM / BK; ++kb) {
    if (kb + 1 < HDIM / BK) {
      int nb = buf ^ 1;
      int ko = (kb + 1) * BK;
#pragma unroll
      for (int i = 0; i < 4; ++i) gload16(aptr[i] + ko, &lds[nb][adst[i]]);
#pragma unroll
      for (int i = 0; i < 2; ++i) gload16(bptr[i] + ko, &lds[nb][bdst[i]]);
    }

    bf16x8 af[2][4], bfr[2][2];
#pragma unroll
    for (int kk = 0; kk < 2; ++kk) {
#pragma unroll
      for (int m = 0; m < 4; ++m) af[kk][m] = *(const bf16x8*)(&lds[buf][aoffr[kk][m]]);
#pragma unroll
      for (int n = 0; n < 2; ++n) bfr[kk][n] = *(const bf16x8*)(&lds[buf][boffr[kk][n]]);
    }
#pragma unroll
    for (int kk = 0; kk < 2; ++kk)
#pragma unroll
      for (int m = 0; m < 4; ++m)
#pragma unroll
        for (int n = 0; n < 2; ++n)
          acc[m][n] = __builtin_amdgcn_mfma_f32_16x16x32_bf16(af[kk][m], bfr[kk][n], acc[m][n], 0, 0, 0);

    __syncthreads();   // drains vmcnt (staged nb complete) + all reads of buf done
    buf ^= 1;
  }

  // Epilogue: C/D layout col = lane&15, row = (lane>>4)*4 + j  [m89/m91]
#pragma unroll
  for (int m = 0; m < 4; ++m) {
#pragma unroll
    for (int j = 0; j < 4; ++j) {
      int rloc = wr + m * 16 + lk * 4 + j;
      int grow = mt * BM + rloc;
      if (grow < cnt) {
        int tok = list_tok[off + grow];
        float gw = list_w[off + grow];
        float* orow = out + (size_t)tok * HDIM + nt * BN + wc;
        const float* brow = expert_b + e * HDIM + nt * BN + wc;
#pragma unroll
        for (int n = 0; n < 2; ++n) {
          int dcol = n * 16 + lr;
          float v = acc[m][n][j] + brow[dcol];
          v = fmaxf(v, 0.f) * gw;
          atomicAdd(orow + dcol, v);
        }
      }
    }
  }
}

extern "C" void kernel_launch(void* const* d_in, const int* in_sizes, int n_in,
                              void* d_out, int out_size, void* d_ws, size_t ws_size,
                              hipStream_t stream) {
  const float* tokens = (const float*)d_in[0];
  const float* gate_w = (const float*)d_in[1];
  const float* expert_w = (const float*)d_in[2];
  const float* expert_b = (const float*)d_in[3];
  float* out = (float*)d_out;

  int* counts = (int*)d_ws;                 // 16
  int* offsets = counts + 16;               // 16
  int* cursor = offsets + 16;               // 16
  int* tok_idx = cursor + 16;               // TOKENS*2
  float* tok_w = (float*)(tok_idx + TOKENS * 2);
  int* list_tok = (int*)(tok_w + TOKENS * 2);
  float* list_w = (float*)(list_tok + TOKENS * 2);
  // align bf16 buffers to 256B
  size_t head = (size_t)(list_w + TOKENS * 2) - (size_t)d_ws;
  head = (head + 255) & ~(size_t)255;
  __bf16* w_bf = (__bf16*)((char*)d_ws + head);                    // 32 MB
  __bf16* tok_bf = w_bf + (size_t)NEXP * HDIM * HDIM;              // 8 MB

  hipMemsetAsync(counts, 0, 16 * sizeof(int), stream);
  hipMemsetAsync(d_out, 0, (size_t)out_size * sizeof(float), stream);

  convert_kernel<<<2048, 256, 0, stream>>>(expert_w, tokens, w_bf, tok_bf);
  gate_kernel<<<TOKENS / 4, 256, 0, stream>>>(tokens, gate_w, counts, tok_idx, tok_w);
  scan_kernel<<<1, 64, 0, stream>>>(counts, offsets, cursor);
  scatter_kernel<<<TOKENS / 256, 256, 0, stream>>>(tok_idx, tok_w, cursor, list_tok, list_w);

  dim3 grid(NEXP * MAXMT, HDIM / BN);
  moe_gemm_kernel<<<grid, 256, 0, stream>>>(tok_bf, w_bf, expert_b, counts, offsets,
                                            list_tok, list_w, out);
}

// Round 3
// 236.906 us; speedup vs baseline: 1.4565x; 1.3333x over previous
//
#include <hip/hip_runtime.h>
#include <hip/hip_bf16.h>

#define TOKENS 4096
#define HDIM 1024
#define NEXP 16
#define BM 128
#define BN 128
#define BK 64
#define MAXMT (TOKENS / BM)   // 32

typedef __bf16 bf16x8 __attribute__((ext_vector_type(8)));
typedef __bf16 bf16x4 __attribute__((ext_vector_type(4)));
typedef float f32x4 __attribute__((ext_vector_type(4)));

__device__ inline void gload16(const void* g, const void* l) {
  __builtin_amdgcn_global_load_lds((const __attribute__((address_space(1))) void*)g,
                                   (__attribute__((address_space(3))) void*)l, 16, 0, 0);
}

// ---------------- fp32 -> bf16 conversion (weights + tokens) ----------------
#define WQ (NEXP * HDIM * HDIM / 4)   // 4,194,304 float4s
#define TQ (TOKENS * HDIM / 4)        // 1,048,576
__global__ __launch_bounds__(256) void convert_kernel(
    const float* __restrict__ w, const float* __restrict__ t,
    __bf16* __restrict__ wbf, __bf16* __restrict__ tbf) {
  int idx = blockIdx.x * 256 + threadIdx.x;
  for (int i = idx; i < WQ + TQ; i += gridDim.x * 256) {
    const float4* src;
    bf16x4* dst;
    int j;
    if (i < WQ) { src = (const float4*)w; dst = (bf16x4*)wbf; j = i; }
    else        { src = (const float4*)t; dst = (bf16x4*)tbf; j = i - WQ; }
    float4 f = src[j];
    bf16x4 v;
    v[0] = (__bf16)f.x; v[1] = (__bf16)f.y; v[2] = (__bf16)f.z; v[3] = (__bf16)f.w;
    dst[j] = v;
  }
}

// ---------------- Gate: fp32-exact logits, softmax, top-2 (NO atomics) ----------------
__global__ __launch_bounds__(256) void gate_kernel(
    const float* __restrict__ tokens, const float* __restrict__ gate_w,
    int* __restrict__ tok_idx, float* __restrict__ tok_w) {
  int lane = threadIdx.x & 63;
  int wv = threadIdx.x >> 6;
  int token = blockIdx.x * 4 + wv;   // grid = TOKENS/4
  const float* trow = tokens + (size_t)token * HDIM;

  float4 tv[4];
#pragma unroll
  for (int s = 0; s < 4; ++s) tv[s] = *(const float4*)(trow + s * 256 + lane * 4);

  float lg[NEXP];
#pragma unroll
  for (int e = 0; e < NEXP; ++e) {
    float d = 0.f;
#pragma unroll
    for (int s = 0; s < 4; ++s) {
      float4 g = *(const float4*)(gate_w + e * HDIM + s * 256 + lane * 4);
      d += tv[s].x * g.x + tv[s].y * g.y + tv[s].z * g.z + tv[s].w * g.w;
    }
#pragma unroll
    for (int off = 32; off; off >>= 1) d += __shfl_xor(d, off);
    lg[e] = d;
  }

  int i0 = 0; float b0 = lg[0];
#pragma unroll
  for (int e = 1; e < NEXP; ++e) if (lg[e] > b0) { b0 = lg[e]; i0 = e; }
  int i1 = -1; float b1 = -1e30f;
#pragma unroll
  for (int e = 0; e < NEXP; ++e) {
    if (e == i0) continue;
    if (lg[e] > b1) { b1 = lg[e]; i1 = e; }
  }
  float s = 0.f;
#pragma unroll
  for (int e = 0; e < NEXP; ++e) s += expf(lg[e] - b0);
  float w0 = 1.0f / s;               // expf(b0-b0)/s
  float w1 = expf(b1 - b0) / s;

  if (lane == 0) {
    tok_idx[token * 2 + 0] = i0;
    tok_idx[token * 2 + 1] = i1;
    tok_w[token * 2 + 0] = w0;
    tok_w[token * 2 + 1] = w1;
  }
}

// ---------------- Per-expert list compaction (LDS cursor, no global atomics) ----------------
__global__ __launch_bounds__(256) void build_lists_kernel(
    const int* __restrict__ tok_idx, const float* __restrict__ tok_w,
    int* __restrict__ counts, int* __restrict__ list_tok, float* __restrict__ list_w) {
  int e = blockIdx.x;   // 16 blocks
  __shared__ int cur;
  if (threadIdx.x == 0) cur = 0;
  __syncthreads();
  for (int s = threadIdx.x; s < TOKENS * 2; s += 256) {
    if (tok_idx[s] == e) {
      int pos = atomicAdd(&cur, 1);   // LDS atomic — on-CU, cheap
      list_tok[e * TOKENS + pos] = s >> 1;
      list_w[e * TOKENS + pos] = tok_w[s];
    }
  }
  __syncthreads();
  if (threadIdx.x == 0) counts[e] = cur;
}

// ---------------- Grouped GEMM (bf16, global_load_lds, dbuf, 128x128 tile) ----------------
// LDS per buffer: A[128][64] then B[128][64] bf16, XOR swizzle via pre-swizzled
// GLOBAL source column (m173): slot (r,kc) holds G(r, kc^(r&7)).
__global__ __launch_bounds__(256) void moe_gemm_kernel(
    const __bf16* __restrict__ tok_bf, const __bf16* __restrict__ w_bf,
    const float* __restrict__ expert_b, const int* __restrict__ counts,
    const int* __restrict__ list_tok, const float* __restrict__ list_w,
    float* __restrict__ out) {
  int e = blockIdx.x & 15;
  int mt = blockIdx.x >> 4;
  int cnt = counts[e];
  if (mt * BM >= cnt) return;
  int nt = blockIdx.y;
  const int lbase = e * TOKENS;

  __shared__ __bf16 lds[2][(BM + BN) * BK];   // 2 x 32 KB

  int tid = threadIdx.x;
  int lane = tid & 63;
  int wv = tid >> 6;

  // staging: A and B each 1024 16B-chunks; wave wv, issue i covers chunk (wv*4+i)*64+lane
  const __bf16* aptr[4];
  const __bf16* bptr[4];
  int dstb[4];
#pragma unroll
  for (int i = 0; i < 4; ++i) {
    int c = (wv * 4 + i) * 64 + lane;
    int r = c >> 3, kc = c & 7;
    int gr = mt * BM + r;
    int tok = list_tok[lbase + ((gr < cnt) ? gr : (cnt - 1))];
    aptr[i] = tok_bf + (size_t)tok * HDIM + (kc ^ (r & 7)) * 8;
    int d = nt * BN + r;
    bptr[i] = w_bf + (size_t)e * HDIM * HDIM + (size_t)d * HDIM + (kc ^ (r & 7)) * 8;
    dstb[i] = (wv * 4 + i) * 512;   // wave-uniform base (elems); HW adds lane*16B
  }

  int wr = (wv >> 1) * 64;
  int wc = (wv & 1) * 64;
  int lr = lane & 15;
  int lk = lane >> 4;

  int aoffr[2][4], boffr[2][4];
#pragma unroll
  for (int kk = 0; kk < 2; ++kk) {
#pragma unroll
    for (int m = 0; m < 4; ++m) {
      int r = wr + m * 16 + lr;
      aoffr[kk][m] = r * BK + (((kk * 4 + lk) ^ (r & 7)) * 8);
      int d = wc + m * 16 + lr;
      boffr[kk][m] = BM * BK + d * BK + (((kk * 4 + lk) ^ (d & 7)) * 8);
    }
  }

  f32x4 acc[4][4] = {};

  // prologue: stage kb=0 into buf 0
#pragma unroll
  for (int i = 0; i < 4; ++i) gload16(aptr[i], &lds[0][dstb[i]]);
#pragma unroll
  for (int i = 0; i < 4; ++i) gload16(bptr[i], &lds[0][BM * BK + dstb[i]]);
  __syncthreads();

  int buf = 0;
  for (int kb = 0; kb < HDIM / BK; ++kb) {
    if (kb + 1 < HDIM / BK) {
      int nb = buf ^ 1;
      int ko = (kb + 1) * BK;
#pragma unroll
      for (int i = 0; i < 4; ++i) gload16(aptr[i] + ko, &lds[nb][dstb[i]]);
#pragma unroll
      for (int i = 0; i < 4; ++i) gload16(bptr[i] + ko, &lds[nb][BM * BK + dstb[i]]);
    }

    bf16x8 af[2][4], bfr[2][4];
#pragma unroll
    for (int kk = 0; kk < 2; ++kk) {
#pragma unroll
      for (int m = 0; m < 4; ++m) {
        af[kk][m] = *(const bf16x8*)(&lds[buf][aoffr[kk][m]]);
        bfr[kk][m] = *(const bf16x8*)(&lds[buf][boffr[kk][m]]);
      }
    }
#pragma unroll
    for (int kk = 0; kk < 2; ++kk)
#pragma unroll
      for (int m = 0; m < 4; ++m)
#pragma unroll
        for (int n = 0; n < 4; ++n)
          acc[m][n] = __builtin_amdgcn_mfma_f32_16x16x32_bf16(af[kk][m], bfr[kk][n], acc[m][n], 0, 0, 0);

    __syncthreads();
    buf ^= 1;
  }

  // Epilogue: C/D layout col = lane&15, row = (lane>>4)*4 + j
#pragma unroll
  for (int m = 0; m < 4; ++m) {
#pragma unroll
    for (int j = 0; j < 4; ++j) {
      int rloc = wr + m * 16 + lk * 4 + j;
      int grow = mt * BM + rloc;
      if (grow < cnt) {
        int tok = list_tok[lbase + grow];
        float gw = list_w[lbase + grow];
        float* orow = out + (size_t)tok * HDIM + nt * BN + wc;
        const float* brow = expert_b + e * HDIM + nt * BN + wc;
#pragma unroll
        for (int n = 0; n < 4; ++n) {
          int dcol = n * 16 + lr;
          float v = acc[m][n][j] + brow[dcol];
          v = fmaxf(v, 0.f) * gw;
          atomicAdd(orow + dcol, v);
        }
      }
    }
  }
}

extern "C" void kernel_launch(void* const* d_in, const int* in_sizes, int n_in,
                              void* d_out, int out_size, void* d_ws, size_t ws_size,
                              hipStream_t stream) {
  const float* tokens = (const float*)d_in[0];
  const float* gate_w = (const float*)d_in[1];
  const float* expert_w = (const float*)d_in[2];
  const float* expert_b = (const float*)d_in[3];
  float* out = (float*)d_out;

  int* counts = (int*)d_ws;                       // 16
  int* tok_idx = counts + 16;                     // TOKENS*2
  float* tok_w = (float*)(tok_idx + TOKENS * 2);  // TOKENS*2
  int* list_tok = (int*)(tok_w + TOKENS * 2);     // NEXP*TOKENS
  float* list_w = (float*)(list_tok + NEXP * TOKENS); // NEXP*TOKENS
  size_t head = (size_t)(list_w + NEXP * TOKENS) - (size_t)d_ws;
  head = (head + 255) & ~(size_t)255;
  __bf16* w_bf = (__bf16*)((char*)d_ws + head);           // 32 MB
  __bf16* tok_bf = w_bf + (size_t)NEXP * HDIM * HDIM;     // 8 MB

  hipMemsetAsync(d_out, 0, (size_t)out_size * sizeof(float), stream);

  convert_kernel<<<2048, 256, 0, stream>>>(expert_w, tokens, w_bf, tok_bf);
  gate_kernel<<<TOKENS / 4, 256, 0, stream>>>(tokens, gate_w, tok_idx, tok_w);
  build_lists_kernel<<<NEXP, 256, 0, stream>>>(tok_idx, tok_w, counts, list_tok, list_w);

  dim3 grid(NEXP * MAXMT, HDIM / BN);
  moe_gemm_kernel<<<grid, 256, 0, stream>>>(tok_bf, w_bf, expert_b, counts,
                                            list_tok, list_w, out);
}

// Round 4
// 227.687 us; speedup vs baseline: 1.5155x; 1.0405x over previous
//
#include <hip/hip_runtime.h>
#include <hip/hip_bf16.h>

#define TOKENS 4096
#define HDIM 1024
#define NEXP 16
#define BM 128
#define BN 128
#define BK 64
#define MAX_TILES (TOKENS * 2 / BM + NEXP)   // 80 upper bound on Σ ceil(cnt_e/BM)

typedef __bf16 bf16x8 __attribute__((ext_vector_type(8)));
typedef float f32x4 __attribute__((ext_vector_type(4)));

__device__ inline void gload16(const void* g, const void* l) {
  __builtin_amdgcn_global_load_lds((const __attribute__((address_space(1))) void*)g,
                                   (__attribute__((address_space(3))) void*)l, 16, 0, 0);
}

// ---------------- fp32 -> bf16, 8 elems/thread, loop-free ----------------
__global__ __launch_bounds__(256) void cvt_kernel(const float* __restrict__ src,
                                                  __bf16* __restrict__ dst) {
  int i = blockIdx.x * 256 + threadIdx.x;
  float4 a = ((const float4*)src)[i * 2];
  float4 b = ((const float4*)src)[i * 2 + 1];
  bf16x8 v;
  v[0] = (__bf16)a.x; v[1] = (__bf16)a.y; v[2] = (__bf16)a.z; v[3] = (__bf16)a.w;
  v[4] = (__bf16)b.x; v[5] = (__bf16)b.y; v[6] = (__bf16)b.z; v[7] = (__bf16)b.w;
  ((bf16x8*)dst)[i] = v;
}

// ---------------- Gate: fp32-exact logits, softmax, top-2 (no atomics) ----------------
__global__ __launch_bounds__(256) void gate_kernel(
    const float* __restrict__ tokens, const float* __restrict__ gate_w,
    int* __restrict__ tok_idx, float* __restrict__ tok_w) {
  int lane = threadIdx.x & 63;
  int wv = threadIdx.x >> 6;
  int token = blockIdx.x * 4 + wv;
  const float* trow = tokens + (size_t)token * HDIM;

  float4 tv[4];
#pragma unroll
  for (int s = 0; s < 4; ++s) tv[s] = *(const float4*)(trow + s * 256 + lane * 4);

  float lg[NEXP];
#pragma unroll
  for (int e = 0; e < NEXP; ++e) {
    float d = 0.f;
#pragma unroll
    for (int s = 0; s < 4; ++s) {
      float4 g = *(const float4*)(gate_w + e * HDIM + s * 256 + lane * 4);
      d += tv[s].x * g.x + tv[s].y * g.y + tv[s].z * g.z + tv[s].w * g.w;
    }
#pragma unroll
    for (int off = 32; off; off >>= 1) d += __shfl_xor(d, off);
    lg[e] = d;
  }

  int i0 = 0; float b0 = lg[0];
#pragma unroll
  for (int e = 1; e < NEXP; ++e) if (lg[e] > b0) { b0 = lg[e]; i0 = e; }
  int i1 = -1; float b1 = -1e30f;
#pragma unroll
  for (int e = 0; e < NEXP; ++e) {
    if (e == i0) continue;
    if (lg[e] > b1) { b1 = lg[e]; i1 = e; }
  }
  float s = 0.f;
#pragma unroll
  for (int e = 0; e < NEXP; ++e) s += expf(lg[e] - b0);
  float w0 = 1.0f / s;
  float w1 = expf(b1 - b0) / s;

  if (lane == 0) {
    tok_idx[token * 2 + 0] = i0;
    tok_idx[token * 2 + 1] = i1;
    tok_w[token * 2 + 0] = w0;
    tok_w[token * 2 + 1] = w1;
  }
}

// ---------------- Per-expert list compaction (LDS cursor) ----------------
__global__ __launch_bounds__(256) void build_lists_kernel(
    const int* __restrict__ tok_idx, const float* __restrict__ tok_w,
    int* __restrict__ counts, int* __restrict__ list_tok, float* __restrict__ list_w) {
  int e = blockIdx.x;
  __shared__ int cur;
  if (threadIdx.x == 0) cur = 0;
  __syncthreads();
  for (int s = threadIdx.x; s < TOKENS * 2; s += 256) {
    if (tok_idx[s] == e) {
      int pos = atomicAdd(&cur, 1);
      list_tok[e * TOKENS + pos] = s >> 1;
      list_w[e * TOKENS + pos] = tok_w[s];
    }
  }
  __syncthreads();
  if (threadIdx.x == 0) counts[e] = cur;
}

// ---------------- Tile planning: flat (expert, mt) list ----------------
__global__ void plan_kernel(const int* __restrict__ counts, int* __restrict__ tiles,
                            int* __restrict__ n_tiles) {
  if (threadIdx.x == 0) {
    int n = 0;
    for (int e = 0; e < NEXP; ++e) {
      int t = (counts[e] + BM - 1) / BM;
      for (int m = 0; m < t; ++m) { tiles[n * 2] = e; tiles[n * 2 + 1] = m; ++n; }
    }
    *n_tiles = n;
  }
}

// ---------------- Grouped GEMM: 8 waves, 128x128 tile, dbuf gload_lds ----------------
// LDS per buffer: A[128][64] then B[128][64] bf16; XOR swizzle via pre-swizzled
// GLOBAL source column (m173): slot (r,kc) holds G(r, kc^(r&7)).
__global__ __launch_bounds__(512, 4) void moe_gemm_kernel(
    const __bf16* __restrict__ tok_bf, const __bf16* __restrict__ w_bf,
    const float* __restrict__ expert_b, const int* __restrict__ counts,
    const int* __restrict__ tiles, const int* __restrict__ n_tiles,
    const int* __restrict__ list_tok, const float* __restrict__ list_w,
    float* __restrict__ out) {
  int bx = blockIdx.x;
  if (bx >= *n_tiles) return;
  int e = tiles[bx * 2];
  int mt = tiles[bx * 2 + 1];
  int cnt = counts[e];
  int nt = blockIdx.y;
  const int lbase = e * TOKENS;

  __shared__ __bf16 lds[2][(BM + BN) * BK];   // 2 x 32 KB

  int tid = threadIdx.x;
  int lane = tid & 63;
  int wv = tid >> 6;   // 0..7

  // staging: A and B each 1024 16B-chunks; wave wv issue i in {0,1}: chunk (wv*2+i)*64+lane
  const __bf16* aptr[2];
  const __bf16* bptr[2];
  int dstb[2];
#pragma unroll
  for (int i = 0; i < 2; ++i) {
    int c = (wv * 2 + i) * 64 + lane;
    int r = c >> 3, kc = c & 7;
    int gr = mt * BM + r;
    int tok = list_tok[lbase + ((gr < cnt) ? gr : (cnt - 1))];
    aptr[i] = tok_bf + (size_t)tok * HDIM + (kc ^ (r & 7)) * 8;
    int d = nt * BN + r;
    bptr[i] = w_bf + (size_t)e * HDIM * HDIM + (size_t)d * HDIM + (kc ^ (r & 7)) * 8;
    dstb[i] = (wv * 2 + i) * 512;   // wave-uniform base (elems); HW adds lane*16B
  }

  int wr = (wv >> 2) * 64;   // 0 / 64
  int wc = (wv & 3) * 32;    // 0 / 32 / 64 / 96
  int lr = lane & 15;
  int lk = lane >> 4;

  int aoffr[2][4], boffr[2][2];
#pragma unroll
  for (int kk = 0; kk < 2; ++kk) {
#pragma unroll
    for (int m = 0; m < 4; ++m) {
      int r = wr + m * 16 + lr;
      aoffr[kk][m] = r * BK + (((kk * 4 + lk) ^ (r & 7)) * 8);
    }
#pragma unroll
    for (int n = 0; n < 2; ++n) {
      int d = wc + n * 16 + lr;
      boffr[kk][n] = BM * BK + d * BK + (((kk * 4 + lk) ^ (d & 7)) * 8);
    }
  }

  f32x4 acc[4][2] = {};

  // prologue: stage kb=0 into buf 0
#pragma unroll
  for (int i = 0; i < 2; ++i) gload16(aptr[i], &lds[0][dstb[i]]);
#pragma unroll
  for (int i = 0; i < 2; ++i) gload16(bptr[i], &lds[0][BM * BK + dstb[i]]);
  __syncthreads();

  int buf = 0;
  for (int kb = 0; kb < HDIM / BK; ++kb) {
    if (kb + 1 < HDIM / BK) {
      int nb = buf ^ 1;
      int ko = (kb + 1) * BK;
#pragma unroll
      for (int i = 0; i < 2; ++i) gload16(aptr[i] + ko, &lds[nb][dstb[i]]);
#pragma unroll
      for (int i = 0; i < 2; ++i) gload16(bptr[i] + ko, &lds[nb][BM * BK + dstb[i]]);
    }

    bf16x8 af[2][4], bfr[2][2];
#pragma unroll
    for (int kk = 0; kk < 2; ++kk) {
#pragma unroll
      for (int m = 0; m < 4; ++m) af[kk][m] = *(const bf16x8*)(&lds[buf][aoffr[kk][m]]);
#pragma unroll
      for (int n = 0; n < 2; ++n) bfr[kk][n] = *(const bf16x8*)(&lds[buf][boffr[kk][n]]);
    }
#pragma unroll
    for (int kk = 0; kk < 2; ++kk)
#pragma unroll
      for (int m = 0; m < 4; ++m)
#pragma unroll
        for (int n = 0; n < 2; ++n)
          acc[m][n] = __builtin_amdgcn_mfma_f32_16x16x32_bf16(af[kk][m], bfr[kk][n], acc[m][n], 0, 0, 0);

    __syncthreads();
    buf ^= 1;
  }

  // Epilogue: C/D layout col = lane&15, row = (lane>>4)*4 + j
#pragma unroll
  for (int m = 0; m < 4; ++m) {
#pragma unroll
    for (int j = 0; j < 4; ++j) {
      int rloc = wr + m * 16 + lk * 4 + j;
      int grow = mt * BM + rloc;
      if (grow < cnt) {
        int tok = list_tok[lbase + grow];
        float gw = list_w[lbase + grow];
        float* orow = out + (size_t)tok * HDIM + nt * BN + wc;
        const float* brow = expert_b + e * HDIM + nt * BN + wc;
#pragma unroll
        for (int n = 0; n < 2; ++n) {
          int dcol = n * 16 + lr;
          float v = acc[m][n][j] + brow[dcol];
          v = fmaxf(v, 0.f) * gw;
          atomicAdd(orow + dcol, v);
        }
      }
    }
  }
}

extern "C" void kernel_launch(void* const* d_in, const int* in_sizes, int n_in,
                              void* d_out, int out_size, void* d_ws, size_t ws_size,
                              hipStream_t stream) {
  const float* tokens = (const float*)d_in[0];
  const float* gate_w = (const float*)d_in[1];
  const float* expert_w = (const float*)d_in[2];
  const float* expert_b = (const float*)d_in[3];
  float* out = (float*)d_out;

  int* counts = (int*)d_ws;                           // 16
  int* n_tiles = counts + 16;                         // 1 (+pad)
  int* tiles = n_tiles + 16;                          // MAX_TILES*2
  int* tok_idx = tiles + MAX_TILES * 2;               // TOKENS*2
  float* tok_w = (float*)(tok_idx + TOKENS * 2);      // TOKENS*2
  int* list_tok = (int*)(tok_w + TOKENS * 2);         // NEXP*TOKENS
  float* list_w = (float*)(list_tok + NEXP * TOKENS); // NEXP*TOKENS
  size_t head = (size_t)(list_w + NEXP * TOKENS) - (size_t)d_ws;
  head = (head + 255) & ~(size_t)255;
  __bf16* w_bf = (__bf16*)((char*)d_ws + head);           // 32 MB
  __bf16* tok_bf = w_bf + (size_t)NEXP * HDIM * HDIM;     // 8 MB

  hipMemsetAsync(d_out, 0, (size_t)out_size * sizeof(float), stream);

  cvt_kernel<<<NEXP * HDIM * HDIM / 8 / 256, 256, 0, stream>>>(expert_w, w_bf);
  cvt_kernel<<<TOKENS * HDIM / 8 / 256, 256, 0, stream>>>(tokens, tok_bf);
  gate_kernel<<<TOKENS / 4, 256, 0, stream>>>(tokens, gate_w, tok_idx, tok_w);
  build_lists_kernel<<<NEXP, 256, 0, stream>>>(tok_idx, tok_w, counts, list_tok, list_w);
  plan_kernel<<<1, 64, 0, stream>>>(counts, tiles, n_tiles);

  dim3 grid(MAX_TILES, HDIM / BN);
  moe_gemm_kernel<<<grid, 512, 0, stream>>>(tok_bf, w_bf, expert_b, counts, tiles, n_tiles,
                                            list_tok, list_w, out);
}